// Round 1
// baseline (548.124 us; speedup 1.0000x reference)
//
#include <hip/hip_runtime.h>
#include <hip/hip_bf16.h>
#include <stdint.h>

#define NBATCH 512
#define FDIM   512   // graph_feat_size
#define NATOM  128   // N
#define KDIM   256   // attention K

// LDS tile strides (bf16 elements). 40*2B = 80 B row stride:
//  - keeps 16B alignment for ds_read_b128 fragments (80 % 16 == 0)
//  - fragment reads are only 2-way bank-aliased (free on CDNA4, m136)
#define VS_STRIDE 40
#define WS_STRIDE 40

typedef __attribute__((ext_vector_type(8))) __bf16        bf16x8;
typedef __attribute__((ext_vector_type(8))) unsigned short ushort8;
typedef __attribute__((ext_vector_type(4))) float          f32x4;

__device__ __forceinline__ float fast_tanh(float x) {
    // tanh(x) = 1 - 2/(exp(2x)+1); saturates correctly for |x| large
    float e = __expf(2.0f * x);
    return 1.0f - 2.0f / (e + 1.0f);
}

__device__ __forceinline__ unsigned short bf16_rne(float f) {
    unsigned int u = __float_as_uint(f);
    u += 0x7FFFu + ((u >> 16) & 1u);   // round-to-nearest-even
    return (unsigned short)(u >> 16);
}

__global__ __launch_bounds__(512, 2)
void coattn_kernel(const float* __restrict__ V_n, const float* __restrict__ Q_n,
                   const float* __restrict__ W_m, const float* __restrict__ W_v,
                   const float* __restrict__ W_q, const float* __restrict__ W_h,
                   float* __restrict__ out)
{
    __shared__ unsigned short Ws[KDIM * WS_STRIDE];    // 20480 B: W tile [256 k][32 f] bf16
    __shared__ unsigned short VsT[NATOM * VS_STRIDE];  // 10240 B: V tile transposed [128 n][32 f] bf16
    __shared__ float rsV[FDIM];
    __shared__ float rsQ[FDIM];
    __shared__ float m0s[FDIM];
    __shared__ float cgate[KDIM];                      // tanh(W_m@M0)[k] * W_h[k]
    __shared__ float s_lds[NATOM];
    __shared__ float alpha_lds[NATOM];

    const int b    = blockIdx.x;
    const int t    = threadIdx.x;
    const int lane = t & 63;
    const int wid  = t >> 6;      // 0..7
    const int wr   = wid >> 1;    // 0..3 : k-block of 64
    const int wc   = wid & 1;     // 0..1 : n-block of 64
    const int l15  = lane & 15;
    const int lg   = lane >> 4;   // 0..3

    const float* Vb = V_n + (size_t)b * FDIM * NATOM;
    const float* Qb = Q_n + (size_t)b * FDIM * NATOM;

    f32x4 accV[4][4], accQ[4][4];
    {
        f32x4 z = {0.f, 0.f, 0.f, 0.f};
        #pragma unroll
        for (int i = 0; i < 4; ++i)
            #pragma unroll
            for (int j = 0; j < 4; ++j) { accV[i][j] = z; accQ[i][j] = z; }
    }

    // ---- streamed GEMM: acc[k,n] += W[k,f] * src[f,n], plus rowsum over n ----
    auto stream_gemm = [&](const float* src, const float* W, float* rowsum,
                           f32x4 (&acc)[4][4]) {
        const int fr   = t >> 4;   // 0..31 : f-row within tile
        const int m    = t & 15;
        const int kw   = t >> 1;   // 0..255
        const int part = t & 1;
        for (int s = 0; s < 16; ++s) {
            const int f0 = s * 32;
            __syncthreads();   // previous iteration's fragment reads done

            // stage src rows f0..f0+31 -> VsT (transposed, bf16) + rowsums
            float vv[8];
            float rs = 0.f;
            const float* srow = src + (size_t)(f0 + fr) * NATOM + m;
            #pragma unroll
            for (int i = 0; i < 8; ++i) { vv[i] = srow[16 * i]; rs += vv[i]; }
            rs += __shfl_xor(rs, 1);
            rs += __shfl_xor(rs, 2);
            rs += __shfl_xor(rs, 4);
            rs += __shfl_xor(rs, 8);
            if (m == 0) rowsum[f0 + fr] = rs;
            #pragma unroll
            for (int i = 0; i < 8; ++i)
                VsT[(m + 16 * i) * VS_STRIDE + fr] = bf16_rne(vv[i]);

            // stage W tile [256 x 32] (f32 global -> bf16 LDS)
            {
                const float4* wrow = (const float4*)(W + (size_t)kw * FDIM + f0 + part * 16);
                float4 w0 = wrow[0], w1 = wrow[1], w2 = wrow[2], w3 = wrow[3];
                ushort8 lo, hi;
                lo[0] = bf16_rne(w0.x); lo[1] = bf16_rne(w0.y);
                lo[2] = bf16_rne(w0.z); lo[3] = bf16_rne(w0.w);
                lo[4] = bf16_rne(w1.x); lo[5] = bf16_rne(w1.y);
                lo[6] = bf16_rne(w1.z); lo[7] = bf16_rne(w1.w);
                hi[0] = bf16_rne(w2.x); hi[1] = bf16_rne(w2.y);
                hi[2] = bf16_rne(w2.z); hi[3] = bf16_rne(w2.w);
                hi[4] = bf16_rne(w3.x); hi[5] = bf16_rne(w3.y);
                hi[6] = bf16_rne(w3.z); hi[7] = bf16_rne(w3.w);
                *(ushort8*)&Ws[kw * WS_STRIDE + part * 16]     = lo;
                *(ushort8*)&Ws[kw * WS_STRIDE + part * 16 + 8] = hi;
            }
            __syncthreads();

            // fragments + 16 MFMA (wave tile: 64 k x 64 n)
            bf16x8 af[4], bfr[4];
            #pragma unroll
            for (int mi = 0; mi < 4; ++mi)
                af[mi] = __builtin_bit_cast(bf16x8,
                    *(const ushort8*)&Ws[(wr * 64 + mi * 16 + l15) * WS_STRIDE + lg * 8]);
            #pragma unroll
            for (int ni = 0; ni < 4; ++ni)
                bfr[ni] = __builtin_bit_cast(bf16x8,
                    *(const ushort8*)&VsT[(wc * 64 + ni * 16 + l15) * VS_STRIDE + lg * 8]);
            #pragma unroll
            for (int mi = 0; mi < 4; ++mi)
                #pragma unroll
                for (int ni = 0; ni < 4; ++ni)
                    acc[mi][ni] = __builtin_amdgcn_mfma_f32_16x16x32_bf16(
                        af[mi], bfr[ni], acc[mi][ni], 0, 0, 0);
        }
    };

    stream_gemm(Vb, W_v, rsV, accV);
    stream_gemm(Qb, W_q, rsQ, accQ);

    __syncthreads();
    // ---- M0 = tanh(rsV/64) * tanh(rsQ/64) ----
    m0s[t] = fast_tanh(rsV[t] * 0.015625f) * fast_tanh(rsQ[t] * 0.015625f);
    __syncthreads();

    // ---- gate GEMV: cgate[k] = tanh(W_m[k,:] . M0) * W_h[k] ----
    {
        const float4* m04 = (const float4*)m0s;
        float4 mb0 = m04[2 * lane], mb1 = m04[2 * lane + 1];
        for (int kk = wid; kk < KDIM; kk += 8) {
            const float4* wm4 = (const float4*)(W_m + (size_t)kk * FDIM);
            float4 a0 = wm4[2 * lane], a1 = wm4[2 * lane + 1];
            float sum = a0.x * mb0.x + a0.y * mb0.y + a0.z * mb0.z + a0.w * mb0.w
                      + a1.x * mb1.x + a1.y * mb1.y + a1.z * mb1.z + a1.w * mb1.w;
            #pragma unroll
            for (int o = 1; o < 64; o <<= 1) sum += __shfl_xor(sum, o);
            if (lane == 0) cgate[kk] = fast_tanh(sum) * W_h[kk];
        }
    }
    __syncthreads();

    // ---- per input: s[n] = sum_k cgate[k]*tanh(G[k,n]); softmax; weighted sum ----
    auto finish = [&](const f32x4 (&acc)[4][4], const float* src,
                      float* ovec, float* oalpha) {
        if (t < NATOM) s_lds[t] = 0.f;
        __syncthreads();
        float sp[4] = {0.f, 0.f, 0.f, 0.f};
        #pragma unroll
        for (int mi = 0; mi < 4; ++mi) {
            #pragma unroll
            for (int j = 0; j < 4; ++j) {
                const float c = cgate[wr * 64 + mi * 16 + lg * 4 + j];
                #pragma unroll
                for (int ni = 0; ni < 4; ++ni)
                    sp[ni] += c * fast_tanh(acc[mi][ni][j]);
            }
        }
        #pragma unroll
        for (int ni = 0; ni < 4; ++ni) {
            sp[ni] += __shfl_xor(sp[ni], 16);
            sp[ni] += __shfl_xor(sp[ni], 32);
        }
        if (lg == 0) {
            #pragma unroll
            for (int ni = 0; ni < 4; ++ni)
                atomicAdd(&s_lds[wc * 64 + ni * 16 + l15], sp[ni]);
        }
        __syncthreads();

        if (wid == 0) {   // softmax over 128 by wave 0
            float a  = s_lds[lane];
            float c2 = s_lds[64 + lane];
            float mx = fmaxf(a, c2);
            #pragma unroll
            for (int o = 1; o < 64; o <<= 1) mx = fmaxf(mx, __shfl_xor(mx, o));
            float ea = __expf(a - mx), eb = __expf(c2 - mx);
            float ssum = ea + eb;
            #pragma unroll
            for (int o = 1; o < 64; o <<= 1) ssum += __shfl_xor(ssum, o);
            float inv = 1.0f / ssum;
            ea *= inv; eb *= inv;
            alpha_lds[lane]      = ea;
            alpha_lds[64 + lane] = eb;
            oalpha[b * NATOM + lane]      = ea;
            oalpha[b * NATOM + 64 + lane] = eb;
        }
        __syncthreads();

        // vector[f] = sum_n alpha[n] * src[f,n] ; one row per wave per iter
        float al0 = alpha_lds[2 * lane], al1 = alpha_lds[2 * lane + 1];
        for (int r = 0; r < FDIM / 8; ++r) {
            const int f = r * 8 + wid;
            const float2 v2 = *(const float2*)(src + (size_t)f * NATOM + 2 * lane);
            float sacc = v2.x * al0 + v2.y * al1;
            #pragma unroll
            for (int o = 1; o < 64; o <<= 1) sacc += __shfl_xor(sacc, o);
            if (lane == 0) ovec[b * FDIM + f] = sacc;
        }
    };

    finish(accV, Vb, out,                 out + 2 * NBATCH * FDIM);
    __syncthreads();
    finish(accQ, Qb, out + NBATCH * FDIM, out + 2 * NBATCH * FDIM + NBATCH * NATOM);
}

extern "C" void kernel_launch(void* const* d_in, const int* in_sizes, int n_in,
                              void* d_out, int out_size, void* d_ws, size_t ws_size,
                              hipStream_t stream) {
    (void)in_sizes; (void)n_in; (void)out_size; (void)d_ws; (void)ws_size;
    const float* V_n = (const float*)d_in[0];
    const float* Q_n = (const float*)d_in[1];
    const float* W_m = (const float*)d_in[2];
    const float* W_v = (const float*)d_in[3];
    const float* W_q = (const float*)d_in[4];
    const float* W_h = (const float*)d_in[5];
    float* out = (float*)d_out;
    hipLaunchKernelGGL(coattn_kernel, dim3(NBATCH), dim3(512), 0, stream,
                       V_n, Q_n, W_m, W_v, W_q, W_h, out);
}